// Round 17
// baseline (157.112 us; speedup 1.0000x reference)
//
#include <hip/hip_runtime.h>
#include <hip/hip_bf16.h>
#include <stdint.h>

// LlamaAttention forward, bf16 MFMA pipeline.
// B=2, S=2048, D=1024, H=16, HD=64.

typedef __attribute__((ext_vector_type(8))) short bf16x8;   // 8 bf16 (4 VGPRs) — MFMA A/B frag
typedef __attribute__((ext_vector_type(4))) float f32x4;    // 16x16 MFMA C/D frag

#define DEV static __device__ __forceinline__

DEV unsigned short f2bf(float f) {          // manual RNE (cold paths)
  union { float f; uint32_t i; } u; u.f = f;
  uint32_t r = u.i + 0x7fffu + ((u.i >> 16) & 1u);
  return (unsigned short)(r >> 16);
}

DEV unsigned short f2bfn(float f) {         // native cast -> v_cvt (hot paths)
  union { __hip_bfloat16 h; unsigned short u; } c;
  c.h = __float2bfloat16(f);
  return c.u;
}

DEV float fast_exp2(float x) {              // bare v_exp_f32 (2^x), no libm guards
#if __has_builtin(__builtin_amdgcn_exp2f)
  return __builtin_amdgcn_exp2f(x);
#else
  return exp2f(x);
#endif
}

// async global->LDS, 16B per lane; LDS dest = wave-uniform base + lane*16
#define GL16(g, l) \
  __builtin_amdgcn_global_load_lds((const __attribute__((address_space(1))) void*)(g), \
                                   (__attribute__((address_space(3))) void*)(l), 16, 0, 0)

// ---------------------------------------------------------------------------
// 1) convert f32 -> bf16: hidden (4M), Wq(*0.125*log2e), Wk, Wv, Wo (1M each).
//    Tail blocks (>=8192) build the fused cos/sin float2 table cs[s][hd<32]
//    in d_out scratch (fully overwritten later by the Wo GEMM).
// ---------------------------------------------------------------------------
__global__ __launch_bounds__(256) void convert_all(
    const float* __restrict__ hid, const float* __restrict__ wq,
    const float* __restrict__ wk, const float* __restrict__ wv,
    const float* __restrict__ wo, unsigned short* __restrict__ out,
    const float* __restrict__ cosT, const float* __restrict__ sinT,
    float2* __restrict__ cst)
{
  if (blockIdx.x >= 8192) {                 // cs-table tail: 256 blocks, 65536 elems
    int idx = (blockIdx.x - 8192) * 256 + threadIdx.x;   // [0, 65536)
    int s = idx >> 5, hd = idx & 31;
    cst[idx] = make_float2(cosT[s * 64 + hd], sinT[s * 64 + hd]);
    return;
  }
  long i = ((long)blockIdx.x * 256 + threadIdx.x) * 4;
  const float* src; float scale = 1.0f;
  if (i < 4194304)      { src = hid + i; }
  else if (i < 5242880) { src = wq + (i - 4194304); scale = 0.18033688011112042f; }
  else if (i < 6291456) { src = wk + (i - 5242880); }
  else if (i < 7340032) { src = wv + (i - 6291456); }
  else                  { src = wo + (i - 7340032); }
  float4 v = *(const float4*)src;
  ushort4 o;
  o.x = f2bf(v.x * scale); o.y = f2bf(v.y * scale);
  o.z = f2bf(v.z * scale); o.w = f2bf(v.w * scale);
  *(ushort4*)(out + i) = o;
}

// ---------------------------------------------------------------------------
// 2) NT GEMM: C[M,N] = A[M,K] * B[N,K]^T, K=1024, bf16 in, 128x128 tile, BK=32
//    m97-style staging: global_load_lds dwordx4 into LINEAR LDS [128][32].
//    MODE 0: fused QKV + RoPE. Q,K -> PAIRED layout [B*H][S][32][2] (pair
//            (hd,hd+32) adjacent; identical k-permutation for Q and K keeps
//            QK^T invariant). V -> TRANSPOSED [B*H][64][S].
//    MODE 1: Wo projection -> f32 [4096][1024]
// ---------------------------------------------------------------------------
template<int MODE>
__global__ __launch_bounds__(256) void gemm_bt(
    const unsigned short* __restrict__ A,
    const unsigned short* __restrict__ B0, const unsigned short* __restrict__ B1,
    const unsigned short* __restrict__ B2,
    const float* __restrict__ csT,          // MODE 0: fused float2 cos/sin table
    unsigned short* __restrict__ qws, unsigned short* __restrict__ kws,
    unsigned short* __restrict__ vws, float* __restrict__ outF)
{
  __shared__ unsigned short As[128 * 32];   // linear [row][32], 8KB
  __shared__ unsigned short Bs[128 * 32];
  const int tid  = threadIdx.x;
  const int lane = tid & 63;
  const int wave = tid >> 6;
  const int wr = wave >> 1, wc = wave & 1;
  const int m0 = blockIdx.x * 128;
  const int n0 = blockIdx.y * 128;

  const unsigned short* Bsrc; int nrel; int sel = 0;
  if (MODE == 0) {
    sel  = n0 >> 10;
    Bsrc = (sel == 0) ? B0 : ((sel == 1) ? B1 : B2);
    nrel = n0 & 1023;
  } else { Bsrc = B0; nrel = n0; }

  const int grow = tid >> 2;        // 0..63: row within 64-row half
  const int gcol = (tid & 3) * 8;   // 8-elem chunk
  const int wuni = wave * 512;      // wave-uniform LDS base (ushorts)

  f32x4 acc[4][4] = {};

  for (int k0 = 0; k0 < 1024; k0 += 32) {
    GL16(A    + (long)(m0 + grow)        * 1024 + k0 + gcol, &As[wuni]);
    GL16(A    + (long)(m0 + 64 + grow)   * 1024 + k0 + gcol, &As[2048 + wuni]);
    GL16(Bsrc + (long)(nrel + grow)      * 1024 + k0 + gcol, &Bs[wuni]);
    GL16(Bsrc + (long)(nrel + 64 + grow) * 1024 + k0 + gcol, &Bs[2048 + wuni]);
    __syncthreads();

    bf16x8 af[4], bfr[4];
#pragma unroll
    for (int mi = 0; mi < 4; ++mi)
      af[mi] = *(const bf16x8*)&As[(wr * 64 + mi * 16 + (lane & 15)) * 32 + (lane >> 4) * 8];
#pragma unroll
    for (int ni = 0; ni < 4; ++ni)
      bfr[ni] = *(const bf16x8*)&Bs[(wc * 64 + ni * 16 + (lane & 15)) * 32 + (lane >> 4) * 8];
#pragma unroll
    for (int mi = 0; mi < 4; ++mi)
#pragma unroll
      for (int ni = 0; ni < 4; ++ni)
        acc[mi][ni] = __builtin_amdgcn_mfma_f32_16x16x32_bf16(af[mi], bfr[ni], acc[mi][ni], 0, 0, 0);
    __syncthreads();
  }

  if (MODE == 0) {
    const int h    = ((n0 & 1023) + wc * 64) >> 6;
    const int colb = lane & 15;
    if (sel < 2) {                 // Q or K: RoPE, paired layout [bh][s][32][2]
      unsigned short* dst = (sel == 0) ? qws : kws;
#pragma unroll
      for (int mi = 0; mi < 4; ++mi) {
#pragma unroll
        for (int r = 0; r < 4; ++r) {
          int row = m0 + wr * 64 + mi * 16 + (lane >> 4) * 4 + r;
          int b = row >> 11, s = row & 2047;
          long base = ((long)(b * 16 + h) * 2048 + s) * 64;
#pragma unroll
          for (int ni = 0; ni < 2; ++ni) {
            int hd = ni * 16 + colb;                          // < 32
            float2 cs = *(const float2*)(csT + (long)(s * 32 + hd) * 2);
            float v1 = acc[mi][ni][r];
            float v2 = acc[mi][ni + 2][r];
            ushort2 pr;
            pr.x = f2bf(v1 * cs.x - v2 * cs.y);               // logical hd
            pr.y = f2bf(v2 * cs.x + v1 * cs.y);               // logical hd+32
            *(ushort2*)(dst + base + 2 * hd) = pr;
          }
        }
      }
    } else {                       // V: store TRANSPOSED [bh][hd][s], ushort4 packs
#pragma unroll
      for (int mi = 0; mi < 4; ++mi) {
        int row0 = m0 + wr * 64 + mi * 16 + (lane >> 4) * 4;   // r=0..3 -> s0..s0+3
        int b = row0 >> 11, s0 = row0 & 2047;
        long hbase = (long)(b * 16 + h) * 64;
#pragma unroll
        for (int ni = 0; ni < 4; ++ni) {
          int hd = ni * 16 + colb;
          ushort4 v4;
          v4.x = f2bf(acc[mi][ni][0]); v4.y = f2bf(acc[mi][ni][1]);
          v4.z = f2bf(acc[mi][ni][2]); v4.w = f2bf(acc[mi][ni][3]);
          *(ushort4*)(vws + (hbase + hd) * 2048 + s0) = v4;
        }
      }
    }
  } else {
#pragma unroll
    for (int mi = 0; mi < 4; ++mi)
#pragma unroll
      for (int r = 0; r < 4; ++r) {
        long row = m0 + wr * 64 + mi * 16 + (lane >> 4) * 4 + r;
#pragma unroll
        for (int ni = 0; ni < 4; ++ni)
          outF[row * 1024 + n0 + wc * 64 + ni * 16 + (lane & 15)] = acc[mi][ni][r];
      }
  }
}

// ---------------------------------------------------------------------------
// 3) flash attention — round-14 structure + XOR bank swizzle (T2) on ALL LDS
//    paths (reg-staged, so write AND read sides carry the same involution:
//    16B-chunk index ^= row&7). 16x16 swapped-QK, KVBLK=64, double-buffered,
//    bare v_exp_f32. grid 512 (XCD-swizzled), 4 waves, 32 q-rows/wave.
// ---------------------------------------------------------------------------
#define KSTR 72   // 144B row stride

__global__ __launch_bounds__(256) void attn_fwd(
    const unsigned short* __restrict__ qws, const unsigned short* __restrict__ kws,
    const unsigned short* __restrict__ vtws, unsigned short* __restrict__ attn)
{
  __shared__ unsigned short K2[2][64 * KSTR];       // [buf][key][hd], swizzled
  __shared__ unsigned short V2[2][64 * KSTR];       // [buf][hd][key], swizzled
  __shared__ unsigned short Plds[4][16 * KSTR];     // [q][key] per wave, swizzled
  const int tid = threadIdx.x, lane = tid & 63, wave = tid >> 6;
  const int bid = blockIdx.x;
  const int sid = (bid & 7) * 64 + (bid >> 3);      // XCD swizzle (bijective)
  const int bh = sid >> 4, qb = sid & 15;
  const unsigned short* Qp = qws  + (long)bh * 2048 * 64;
  const unsigned short* Kp = kws  + (long)bh * 2048 * 64;
  const unsigned short* Vp = vtws + (long)bh * 64 * 2048;   // [hd][S]
  const int q0w = qb * 128 + wave * 32;
  const int l15 = lane & 15, l16 = lane >> 4;
  const int lx7 = l15 & 7;                          // row-XOR for frag reads

  bf16x8 qf[2][2];
#pragma unroll
  for (int sb = 0; sb < 2; ++sb)
#pragma unroll
    for (int st = 0; st < 2; ++st)
      qf[sb][st] = *(const bf16x8*)(Qp + (long)(q0w + sb * 16 + l15) * 64 + l16 * 8 + st * 32);

  f32x4 o[2][4] = {};
  float lrow[2] = {};               // per-lane partial row sum for q = l15

  const int kr_  = tid >> 3;        // K staging: key row (0..31, +32p)
  const int kcs_ = (((tid & 7) ^ (kr_ & 7)) << 3);  // K staging chunk, swizzled
  const int vhd_ = tid >> 2;        // V staging: hd row (0..63)
  const int vc0_ = (tid & 3) * 2;   // V staging: chunk base (2 chunks, +p)

  // prologue: tile 0 -> regs -> buf0 (swizzled writes)
  bf16x8 kreg[2], vreg[2];
#pragma unroll
  for (int p = 0; p < 2; ++p) {
    kreg[p] = *(const bf16x8*)(Kp + (long)(p * 32 + kr_) * 64 + (tid & 7) * 8);
    vreg[p] = *(const bf16x8*)(Vp + (long)vhd_ * 2048 + (vc0_ + p) * 8);
  }
#pragma unroll
  for (int p = 0; p < 2; ++p) {
    *(bf16x8*)&K2[0][(p * 32 + kr_) * KSTR + kcs_] = kreg[p];
    *(bf16x8*)&V2[0][vhd_ * KSTR + (((vc0_ + p) ^ (vhd_ & 7)) << 3)] = vreg[p];
  }

  // one tile body: compute buf CUR; prefetch tile (IT+1) and write to buf NXT.
#define TILE_BODY(CUR, NXT, IT)                                                        \
  {                                                                                    \
    __syncthreads();  /* orders: writes of CUR visible; prior reads of NXT done */     \
    const int nt = (IT) + 1;                                                           \
    if (nt < 32) {                                                                     \
      _Pragma("unroll")                                                                \
      for (int p = 0; p < 2; ++p) {                                                    \
        kreg[p] = *(const bf16x8*)(Kp + (long)(nt * 64 + p * 32 + kr_) * 64 + (tid & 7) * 8); \
        vreg[p] = *(const bf16x8*)(Vp + (long)vhd_ * 2048 + nt * 64 + (vc0_ + p) * 8); \
      }                                                                                \
    }                                                                                  \
    bf16x8 kb[2][4], vb[2][4];                                                         \
    _Pragma("unroll")                                                                  \
    for (int st = 0; st < 2; ++st)                                                     \
      _Pragma("unroll")                                                                \
      for (int ni = 0; ni < 4; ++ni) {                                                 \
        const int cswz = ((l16 + 4 * st) ^ lx7) << 3;                                  \
        kb[st][ni] = *(const bf16x8*)&K2[CUR][(ni * 16 + l15) * KSTR + cswz];          \
        vb[st][ni] = *(const bf16x8*)&V2[CUR][(ni * 16 + l15) * KSTR + cswz];          \
      }                                                                                \
    _Pragma("unroll")                                                                  \
    for (int sb = 0; sb < 2; ++sb) {                                                   \
      f32x4 sf[4] = {};                                                                \
      __builtin_amdgcn_s_setprio(1);                                                   \
      _Pragma("unroll")                                                                \
      for (int st = 0; st < 2; ++st)                                                   \
        _Pragma("unroll")                                                              \
        for (int ni = 0; ni < 4; ++ni)                                                 \
          sf[ni] = __builtin_amdgcn_mfma_f32_16x16x32_bf16(kb[st][ni], qf[sb][st], sf[ni], 0, 0, 0); \
      __builtin_amdgcn_s_setprio(0);                                                   \
      _Pragma("unroll")                                                                \
      for (int ni = 0; ni < 4; ++ni) {                                                 \
        float e0 = fast_exp2(sf[ni][0]), e1 = fast_exp2(sf[ni][1]);                    \
        float e2 = fast_exp2(sf[ni][2]), e3 = fast_exp2(sf[ni][3]);                    \
        lrow[sb] += (e0 + e1) + (e2 + e3);                                             \
        uint2 pk;                                                                      \
        pk.x = (uint32_t)f2bfn(e0) | ((uint32_t)f2bfn(e1) << 16);                      \
        pk.y = (uint32_t)f2bfn(e2) | ((uint32_t)f2bfn(e3) << 16);                      \
        const int slotp = ((((ni * 2) + (l16 >> 1)) ^ lx7) << 1) | (l16 & 1);          \
        *(uint2*)&Plds[wave][l15 * KSTR + slotp * 4] = pk;                             \
      }                                                                                \
      __builtin_amdgcn_s_setprio(1);                                                   \
      _Pragma("unroll")                                                                \
      for (int st = 0; st < 2; ++st) {                                                 \
        bf16x8 pa = *(const bf16x8*)&Plds[wave][l15 * KSTR + (((l16 + 4 * st) ^ lx7) << 3)]; \
        _Pragma("unroll")                                                              \
        for (int ni = 0; ni < 4; ++ni)                                                 \
          o[sb][ni] = __builtin_amdgcn_mfma_f32_16x16x32_bf16(pa, vb[st][ni], o[sb][ni], 0, 0, 0); \
      }                                                                                \
      __builtin_amdgcn_s_setprio(0);                                                   \
    }                                                                                  \
    if (nt < 32) {                                                                     \
      _Pragma("unroll")                                                                \
      for (int p = 0; p < 2; ++p) {                                                    \
        *(bf16x8*)&K2[NXT][(p * 32 + kr_) * KSTR + kcs_] = kreg[p];                    \
        *(bf16x8*)&V2[NXT][vhd_ * KSTR + (((vc0_ + p) ^ (vhd_ & 7)) << 3)] = vreg[p];  \
      }                                                                                \
    }                                                                                  \
  }

  for (int it = 0; it < 32; it += 2) {
    TILE_BODY(0, 1, it);
    TILE_BODY(1, 0, it + 1);
  }
#undef TILE_BODY

  // ---- epilogue: reduce l over lane groups (q=l15), redistribute, store ----
  const int b = bh >> 4, h = bh & 15;
  float linv[2];
#pragma unroll
  for (int sb = 0; sb < 2; ++sb) {
    float t = lrow[sb];
    t += __shfl_xor(t, 16, 64);
    t += __shfl_xor(t, 32, 64);
    linv[sb] = 1.0f / t;
  }
#pragma unroll
  for (int sb = 0; sb < 2; ++sb)
#pragma unroll
    for (int r = 0; r < 4; ++r) {
      float lv = __shfl(linv[sb], l16 * 4 + r, 64);   // fetch 1/l for q=(l16*4+r)
      int qrow = q0w + sb * 16 + l16 * 4 + r;
#pragma unroll
      for (int ni = 0; ni < 4; ++ni) {
        float val = o[sb][ni][r] * lv;
        attn[((long)(b * 2048 + qrow) * 16 + h) * 64 + ni * 16 + l15] = f2bfn(val);
      }
    }
}

// ---------------------------------------------------------------------------
// launcher
// ---------------------------------------------------------------------------
extern "C" void kernel_launch(void* const* d_in, const int* in_sizes, int n_in,
                              void* d_out, int out_size, void* d_ws, size_t ws_size,
                              hipStream_t stream)
{
  const float* hid  = (const float*)d_in[0];
  const float* cosT = (const float*)d_in[2];
  const float* sinT = (const float*)d_in[3];
  const float* wq   = (const float*)d_in[4];
  const float* wk   = (const float*)d_in[5];
  const float* wv   = (const float*)d_in[6];
  const float* wo   = (const float*)d_in[7];

  unsigned short* ws   = (unsigned short*)d_ws;
  unsigned short* xbf  = ws;
  unsigned short* wqbf = ws + 4194304;
  unsigned short* wkbf = ws + 5242880;
  unsigned short* wvbf = ws + 6291456;
  unsigned short* wobf = ws + 7340032;
  unsigned short* qws  = ws + 8388608;
  unsigned short* kws  = ws + 12582912;
  unsigned short* vtws = ws + 16777216;   // [bh][hd][S] (transposed V)
  unsigned short* attn = ws;              // reuse xbf (dead after QKV GEMM)
  float* outF = (float*)d_out;
  float2* cstab = (float2*)d_out;         // 512KB scratch; Wo GEMM overwrites all

  convert_all<<<8448, 256, 0, stream>>>(hid, wq, wk, wv, wo, ws, cosT, sinT, cstab);
  gemm_bt<0><<<dim3(32, 24), 256, 0, stream>>>(xbf, wqbf, wkbf, wvbf, (const float*)cstab,
                                               qws, kws, vtws, nullptr);
  attn_fwd<<<512, 256, 0, stream>>>(qws, kws, vtws, attn);
  gemm_bt<1><<<dim3(32, 8), 256, 0, stream>>>(attn, wobf, nullptr, nullptr, nullptr,
                                              nullptr, nullptr, nullptr, outF);
}

// Round 18
// 131.923 us; speedup vs baseline: 1.1909x; 1.1909x over previous
//
#include <hip/hip_runtime.h>
#include <hip/hip_bf16.h>
#include <stdint.h>

// LlamaAttention forward, bf16 MFMA pipeline.
// B=2, S=2048, D=1024, H=16, HD=64.

typedef __attribute__((ext_vector_type(8))) short bf16x8;   // 8 bf16 (4 VGPRs) — MFMA A/B frag
typedef __attribute__((ext_vector_type(4))) float f32x4;    // 16x16 MFMA C/D frag

#define DEV static __device__ __forceinline__

DEV unsigned short f2bf(float f) {          // manual RNE (cold paths)
  union { float f; uint32_t i; } u; u.f = f;
  uint32_t r = u.i + 0x7fffu + ((u.i >> 16) & 1u);
  return (unsigned short)(r >> 16);
}

DEV unsigned short f2bfn(float f) {         // native cast -> v_cvt (hot paths)
  union { __hip_bfloat16 h; unsigned short u; } c;
  c.h = __float2bfloat16(f);
  return c.u;
}

DEV float fast_exp2(float x) {              // bare v_exp_f32 (2^x), no libm guards
#if __has_builtin(__builtin_amdgcn_exp2f)
  return __builtin_amdgcn_exp2f(x);
#else
  return exp2f(x);
#endif
}

// async global->LDS, 16B per lane; LDS dest = wave-uniform base + lane*16
#define GL16(g, l) \
  __builtin_amdgcn_global_load_lds((const __attribute__((address_space(1))) void*)(g), \
                                   (__attribute__((address_space(3))) void*)(l), 16, 0, 0)

// ---------------------------------------------------------------------------
// 1) convert f32 -> bf16: hidden (4M), Wq(*0.125*log2e), Wk, Wv, Wo (1M each).
//    Tail blocks (>=8192) build the fused cos/sin float2 table cs[s][hd<32]
//    in d_out scratch (fully overwritten later by the Wo GEMM).
// ---------------------------------------------------------------------------
__global__ __launch_bounds__(256) void convert_all(
    const float* __restrict__ hid, const float* __restrict__ wq,
    const float* __restrict__ wk, const float* __restrict__ wv,
    const float* __restrict__ wo, unsigned short* __restrict__ out,
    const float* __restrict__ cosT, const float* __restrict__ sinT,
    float2* __restrict__ cst)
{
  if (blockIdx.x >= 8192) {                 // cs-table tail: 256 blocks, 65536 elems
    int idx = (blockIdx.x - 8192) * 256 + threadIdx.x;   // [0, 65536)
    int s = idx >> 5, hd = idx & 31;
    cst[idx] = make_float2(cosT[s * 64 + hd], sinT[s * 64 + hd]);
    return;
  }
  long i = ((long)blockIdx.x * 256 + threadIdx.x) * 4;
  const float* src; float scale = 1.0f;
  if (i < 4194304)      { src = hid + i; }
  else if (i < 5242880) { src = wq + (i - 4194304); scale = 0.18033688011112042f; }
  else if (i < 6291456) { src = wk + (i - 5242880); }
  else if (i < 7340032) { src = wv + (i - 6291456); }
  else                  { src = wo + (i - 7340032); }
  float4 v = *(const float4*)src;
  ushort4 o;
  o.x = f2bf(v.x * scale); o.y = f2bf(v.y * scale);
  o.z = f2bf(v.z * scale); o.w = f2bf(v.w * scale);
  *(ushort4*)(out + i) = o;
}

// ---------------------------------------------------------------------------
// 2) NT GEMM: C[M,N] = A[M,K] * B[N,K]^T, K=1024, bf16 in, 128x128 tile, BK=32
//    m97-style staging: global_load_lds dwordx4 into LINEAR LDS [128][32].
//    Fused QKV + RoPE. Q,K -> PAIRED layout [B*H][S][32][2]; V -> TRANSPOSED
//    [B*H][64][S].
// ---------------------------------------------------------------------------
__global__ __launch_bounds__(256) void gemm_qkv(
    const unsigned short* __restrict__ A,
    const unsigned short* __restrict__ B0, const unsigned short* __restrict__ B1,
    const unsigned short* __restrict__ B2,
    const float* __restrict__ csT,          // fused float2 cos/sin table
    unsigned short* __restrict__ qws, unsigned short* __restrict__ kws,
    unsigned short* __restrict__ vws)
{
  __shared__ unsigned short As[128 * 32];   // linear [row][32], 8KB
  __shared__ unsigned short Bs[128 * 32];
  const int tid  = threadIdx.x;
  const int lane = tid & 63;
  const int wave = tid >> 6;
  const int wr = wave >> 1, wc = wave & 1;
  const int m0 = blockIdx.x * 128;
  const int n0 = blockIdx.y * 128;

  const int sel = n0 >> 10;
  const unsigned short* Bsrc = (sel == 0) ? B0 : ((sel == 1) ? B1 : B2);
  const int nrel = n0 & 1023;

  const int grow = tid >> 2;        // 0..63: row within 64-row half
  const int gcol = (tid & 3) * 8;   // 8-elem chunk
  const int wuni = wave * 512;      // wave-uniform LDS base (ushorts)

  f32x4 acc[4][4] = {};

  for (int k0 = 0; k0 < 1024; k0 += 32) {
    GL16(A    + (long)(m0 + grow)        * 1024 + k0 + gcol, &As[wuni]);
    GL16(A    + (long)(m0 + 64 + grow)   * 1024 + k0 + gcol, &As[2048 + wuni]);
    GL16(Bsrc + (long)(nrel + grow)      * 1024 + k0 + gcol, &Bs[wuni]);
    GL16(Bsrc + (long)(nrel + 64 + grow) * 1024 + k0 + gcol, &Bs[2048 + wuni]);
    __syncthreads();

    bf16x8 af[4], bfr[4];
#pragma unroll
    for (int mi = 0; mi < 4; ++mi)
      af[mi] = *(const bf16x8*)&As[(wr * 64 + mi * 16 + (lane & 15)) * 32 + (lane >> 4) * 8];
#pragma unroll
    for (int ni = 0; ni < 4; ++ni)
      bfr[ni] = *(const bf16x8*)&Bs[(wc * 64 + ni * 16 + (lane & 15)) * 32 + (lane >> 4) * 8];
#pragma unroll
    for (int mi = 0; mi < 4; ++mi)
#pragma unroll
      for (int ni = 0; ni < 4; ++ni)
        acc[mi][ni] = __builtin_amdgcn_mfma_f32_16x16x32_bf16(af[mi], bfr[ni], acc[mi][ni], 0, 0, 0);
    __syncthreads();
  }

  const int h    = ((n0 & 1023) + wc * 64) >> 6;
  const int colb = lane & 15;
  if (sel < 2) {                 // Q or K: RoPE, paired layout [bh][s][32][2]
    unsigned short* dst = (sel == 0) ? qws : kws;
#pragma unroll
    for (int mi = 0; mi < 4; ++mi) {
#pragma unroll
      for (int r = 0; r < 4; ++r) {
        int row = m0 + wr * 64 + mi * 16 + (lane >> 4) * 4 + r;
        int b = row >> 11, s = row & 2047;
        long base = ((long)(b * 16 + h) * 2048 + s) * 64;
#pragma unroll
        for (int ni = 0; ni < 2; ++ni) {
          int hd = ni * 16 + colb;                          // < 32
          float2 cs = *(const float2*)(csT + (long)(s * 32 + hd) * 2);
          float v1 = acc[mi][ni][r];
          float v2 = acc[mi][ni + 2][r];
          ushort2 pr;
          pr.x = f2bf(v1 * cs.x - v2 * cs.y);               // logical hd
          pr.y = f2bf(v2 * cs.x + v1 * cs.y);               // logical hd+32
          *(ushort2*)(dst + base + 2 * hd) = pr;
        }
      }
    }
  } else {                       // V: store TRANSPOSED [bh][hd][s], ushort4 packs
#pragma unroll
    for (int mi = 0; mi < 4; ++mi) {
      int row0 = m0 + wr * 64 + mi * 16 + (lane >> 4) * 4;   // r=0..3 -> s0..s0+3
      int b = row0 >> 11, s0 = row0 & 2047;
      long hbase = (long)(b * 16 + h) * 64;
#pragma unroll
      for (int ni = 0; ni < 4; ++ni) {
        int hd = ni * 16 + colb;
        ushort4 v4;
        v4.x = f2bf(acc[mi][ni][0]); v4.y = f2bf(acc[mi][ni][1]);
        v4.z = f2bf(acc[mi][ni][2]); v4.w = f2bf(acc[mi][ni][3]);
        *(ushort4*)(vws + (hbase + hd) * 2048 + s0) = v4;
      }
    }
  }
}

// ---------------------------------------------------------------------------
// 2b) Wo GEMM, 64x128 tile (grid 64x8 = 512 blocks = 2 blocks/CU for the
//     m114-style implicit overlap the 2-barrier loop needs). Same validated
//     staging/fragment pattern: 1 A-GL16 + 2 B-GL16 per K-step; waves 2x2
//     over 32x64 sub-tiles, acc[2][4]. Output f32 [4096][1024].
// ---------------------------------------------------------------------------
__global__ __launch_bounds__(256) void gemm_wo(
    const unsigned short* __restrict__ A,   // attn bf16 [4096][1024]
    const unsigned short* __restrict__ B0,  // Wo bf16 [1024][1024]
    float* __restrict__ outF)
{
  __shared__ unsigned short As[64 * 32];    // 4KB
  __shared__ unsigned short Bs[128 * 32];   // 8KB
  const int tid  = threadIdx.x;
  const int lane = tid & 63;
  const int wave = tid >> 6;
  const int wr = wave >> 1, wc = wave & 1;  // 2x2 waves, 32x64 each
  const int m0 = blockIdx.x * 64;
  const int n0 = blockIdx.y * 128;

  const int grow = tid >> 2;
  const int gcol = (tid & 3) * 8;
  const int wuni = wave * 512;

  f32x4 acc[2][4] = {};

  for (int k0 = 0; k0 < 1024; k0 += 32) {
    GL16(A  + (long)(m0 + grow)      * 1024 + k0 + gcol, &As[wuni]);
    GL16(B0 + (long)(n0 + grow)      * 1024 + k0 + gcol, &Bs[wuni]);
    GL16(B0 + (long)(n0 + 64 + grow) * 1024 + k0 + gcol, &Bs[2048 + wuni]);
    __syncthreads();

    bf16x8 af[2], bfr[4];
#pragma unroll
    for (int mi = 0; mi < 2; ++mi)
      af[mi] = *(const bf16x8*)&As[(wr * 32 + mi * 16 + (lane & 15)) * 32 + (lane >> 4) * 8];
#pragma unroll
    for (int ni = 0; ni < 4; ++ni)
      bfr[ni] = *(const bf16x8*)&Bs[(wc * 64 + ni * 16 + (lane & 15)) * 32 + (lane >> 4) * 8];
#pragma unroll
    for (int mi = 0; mi < 2; ++mi)
#pragma unroll
      for (int ni = 0; ni < 4; ++ni)
        acc[mi][ni] = __builtin_amdgcn_mfma_f32_16x16x32_bf16(af[mi], bfr[ni], acc[mi][ni], 0, 0, 0);
    __syncthreads();
  }

#pragma unroll
  for (int mi = 0; mi < 2; ++mi)
#pragma unroll
    for (int r = 0; r < 4; ++r) {
      long row = m0 + wr * 32 + mi * 16 + (lane >> 4) * 4 + r;
#pragma unroll
      for (int ni = 0; ni < 4; ++ni)
        outF[row * 1024 + n0 + wc * 64 + ni * 16 + (lane & 15)] = acc[mi][ni][r];
    }
}

// ---------------------------------------------------------------------------
// 3) flash attention — round-14/16 validated version (byte-identical): 16x16
//    swapped-QK, KVBLK=64, LDS double-buffered (1 barrier/tile), bare
//    v_exp_f32 softmax. grid 512 (XCD-swizzled), 4 waves, 32 q-rows/wave.
// ---------------------------------------------------------------------------
#define KSTR 72   // 144B row stride: 16B-aligned, bank-spread

__global__ __launch_bounds__(256) void attn_fwd(
    const unsigned short* __restrict__ qws, const unsigned short* __restrict__ kws,
    const unsigned short* __restrict__ vtws, unsigned short* __restrict__ attn)
{
  __shared__ unsigned short K2[2][64 * KSTR];       // [buf][key][hd]
  __shared__ unsigned short V2[2][64 * KSTR];       // [buf][hd][key]
  __shared__ unsigned short Plds[4][16 * KSTR];     // [q][key] per wave
  const int tid = threadIdx.x, lane = tid & 63, wave = tid >> 6;
  const int bid = blockIdx.x;
  const int sid = (bid & 7) * 64 + (bid >> 3);      // XCD swizzle (bijective)
  const int bh = sid >> 4, qb = sid & 15;
  const unsigned short* Qp = qws  + (long)bh * 2048 * 64;
  const unsigned short* Kp = kws  + (long)bh * 2048 * 64;
  const unsigned short* Vp = vtws + (long)bh * 64 * 2048;   // [hd][S]
  const int q0w = qb * 128 + wave * 32;
  const int l15 = lane & 15, l16 = lane >> 4;

  bf16x8 qf[2][2];
#pragma unroll
  for (int sb = 0; sb < 2; ++sb)
#pragma unroll
    for (int st = 0; st < 2; ++st)
      qf[sb][st] = *(const bf16x8*)(Qp + (long)(q0w + sb * 16 + l15) * 64 + l16 * 8 + st * 32);

  f32x4 o[2][4] = {};
  float lrow[2] = {};               // per-lane partial row sum for q = l15

  const int kr_  = tid >> 3;        // K staging: key row
  const int c0_  = (tid & 7) * 8;   // K staging: hd chunk
  const int vhd_ = tid >> 2;        // V staging: hd row
  const int vko_ = (tid & 3) * 16;  // V staging: key chunk

  // prologue: tile 0 -> regs -> buf0
  bf16x8 kreg[2], vreg[2];
#pragma unroll
  for (int p = 0; p < 2; ++p) {
    kreg[p] = *(const bf16x8*)(Kp + (long)(p * 32 + kr_) * 64 + c0_);
    vreg[p] = *(const bf16x8*)(Vp + (long)vhd_ * 2048 + vko_ + p * 8);
  }
#pragma unroll
  for (int p = 0; p < 2; ++p) {
    *(bf16x8*)&K2[0][(p * 32 + kr_) * KSTR + c0_] = kreg[p];
    *(bf16x8*)&V2[0][vhd_ * KSTR + vko_ + p * 8]  = vreg[p];
  }

  // one tile body: compute buf CUR; prefetch tile (IT+1) and write to buf NXT.
#define TILE_BODY(CUR, NXT, IT)                                                        \
  {                                                                                    \
    __syncthreads();  /* orders: writes of CUR visible; prior reads of NXT done */     \
    const int nt = (IT) + 1;                                                           \
    if (nt < 32) {                                                                     \
      _Pragma("unroll")                                                                \
      for (int p = 0; p < 2; ++p) {                                                    \
        kreg[p] = *(const bf16x8*)(Kp + (long)(nt * 64 + p * 32 + kr_) * 64 + c0_);    \
        vreg[p] = *(const bf16x8*)(Vp + (long)vhd_ * 2048 + nt * 64 + vko_ + p * 8);   \
      }                                                                                \
    }                                                                                  \
    bf16x8 kb[2][4], vb[2][4];                                                         \
    _Pragma("unroll")                                                                  \
    for (int st = 0; st < 2; ++st)                                                     \
      _Pragma("unroll")                                                                \
      for (int ni = 0; ni < 4; ++ni) {                                                 \
        kb[st][ni] = *(const bf16x8*)&K2[CUR][(ni * 16 + l15) * KSTR + l16 * 8 + st * 32]; \
        vb[st][ni] = *(const bf16x8*)&V2[CUR][(ni * 16 + l15) * KSTR + l16 * 8 + st * 32]; \
      }                                                                                \
    _Pragma("unroll")                                                                  \
    for (int sb = 0; sb < 2; ++sb) {                                                   \
      f32x4 sf[4] = {};                                                                \
      __builtin_amdgcn_s_setprio(1);                                                   \
      _Pragma("unroll")                                                                \
      for (int st = 0; st < 2; ++st)                                                   \
        _Pragma("unroll")                                                              \
        for (int ni = 0; ni < 4; ++ni)                                                 \
          sf[ni] = __builtin_amdgcn_mfma_f32_16x16x32_bf16(kb[st][ni], qf[sb][st], sf[ni], 0, 0, 0); \
      __builtin_amdgcn_s_setprio(0);                                                   \
      _Pragma("unroll")                                                                \
      for (int ni = 0; ni < 4; ++ni) {                                                 \
        float e0 = fast_exp2(sf[ni][0]), e1 = fast_exp2(sf[ni][1]);                    \
        float e2 = fast_exp2(sf[ni][2]), e3 = fast_exp2(sf[ni][3]);                    \
        lrow[sb] += (e0 + e1) + (e2 + e3);                                             \
        uint2 pk;                                                                      \
        pk.x = (uint32_t)f2bfn(e0) | ((uint32_t)f2bfn(e1) << 16);                      \
        pk.y = (uint32_t)f2bfn(e2) | ((uint32_t)f2bfn(e3) << 16);                      \
        *(uint2*)&Plds[wave][l15 * KSTR + ni * 16 + l16 * 4] = pk;                     \
      }                                                                                \
      __builtin_amdgcn_s_setprio(1);                                                   \
      _Pragma("unroll")                                                                \
      for (int st = 0; st < 2; ++st) {                                                 \
        bf16x8 pa = *(const bf16x8*)&Plds[wave][l15 * KSTR + l16 * 8 + st * 32];       \
        _Pragma("unroll")                                                              \
        for (int ni = 0; ni < 4; ++ni)                                                 \
          o[sb][ni] = __builtin_amdgcn_mfma_f32_16x16x32_bf16(pa, vb[st][ni], o[sb][ni], 0, 0, 0); \
      }                                                                                \
      __builtin_amdgcn_s_setprio(0);                                                   \
    }                                                                                  \
    if (nt < 32) {                                                                     \
      _Pragma("unroll")                                                                \
      for (int p = 0; p < 2; ++p) {                                                    \
        *(bf16x8*)&K2[NXT][(p * 32 + kr_) * KSTR + c0_] = kreg[p];                     \
        *(bf16x8*)&V2[NXT][vhd_ * KSTR + vko_ + p * 8]  = vreg[p];                     \
      }                                                                                \
    }                                                                                  \
  }

  for (int it = 0; it < 32; it += 2) {
    TILE_BODY(0, 1, it);
    TILE_BODY(1, 0, it + 1);
  }
#undef TILE_BODY

  // ---- epilogue: reduce l over lane groups (q=l15), redistribute, store ----
  const int b = bh >> 4, h = bh & 15;
  float linv[2];
#pragma unroll
  for (int sb = 0; sb < 2; ++sb) {
    float t = lrow[sb];
    t += __shfl_xor(t, 16, 64);
    t += __shfl_xor(t, 32, 64);
    linv[sb] = 1.0f / t;
  }
#pragma unroll
  for (int sb = 0; sb < 2; ++sb)
#pragma unroll
    for (int r = 0; r < 4; ++r) {
      float lv = __shfl(linv[sb], l16 * 4 + r, 64);   // fetch 1/l for q=(l16*4+r)
      int qrow = q0w + sb * 16 + l16 * 4 + r;
#pragma unroll
      for (int ni = 0; ni < 4; ++ni) {
        float val = o[sb][ni][r] * lv;
        attn[((long)(b * 2048 + qrow) * 16 + h) * 64 + ni * 16 + l15] = f2bfn(val);
      }
    }
}

// ---------------------------------------------------------------------------
// launcher
// ---------------------------------------------------------------------------
extern "C" void kernel_launch(void* const* d_in, const int* in_sizes, int n_in,
                              void* d_out, int out_size, void* d_ws, size_t ws_size,
                              hipStream_t stream)
{
  const float* hid  = (const float*)d_in[0];
  const float* cosT = (const float*)d_in[2];
  const float* sinT = (const float*)d_in[3];
  const float* wq   = (const float*)d_in[4];
  const float* wk   = (const float*)d_in[5];
  const float* wv   = (const float*)d_in[6];
  const float* wo   = (const float*)d_in[7];

  unsigned short* ws   = (unsigned short*)d_ws;
  unsigned short* xbf  = ws;
  unsigned short* wqbf = ws + 4194304;
  unsigned short* wkbf = ws + 5242880;
  unsigned short* wvbf = ws + 6291456;
  unsigned short* wobf = ws + 7340032;
  unsigned short* qws  = ws + 8388608;
  unsigned short* kws  = ws + 12582912;
  unsigned short* vtws = ws + 16777216;   // [bh][hd][S] (transposed V)
  unsigned short* attn = ws;              // reuse xbf (dead after QKV GEMM)
  float* outF = (float*)d_out;
  float2* cstab = (float2*)d_out;         // 512KB scratch; Wo GEMM overwrites all

  convert_all<<<8448, 256, 0, stream>>>(hid, wq, wk, wv, wo, ws, cosT, sinT, cstab);
  gemm_qkv<<<dim3(32, 24), 256, 0, stream>>>(xbf, wqbf, wkbf, wvbf, (const float*)cstab,
                                             qws, kws, vtws);
  attn_fwd<<<512, 256, 0, stream>>>(qws, kws, vtws, attn);
  gemm_wo<<<dim3(64, 8), 256, 0, stream>>>(attn, wobf, outF);
}

// Round 20
// 130.965 us; speedup vs baseline: 1.1997x; 1.0073x over previous
//
#include <hip/hip_runtime.h>
#include <hip/hip_bf16.h>
#include <stdint.h>

// LlamaAttention forward, bf16 MFMA pipeline.
// B=2, S=2048, D=1024, H=16, HD=64.

typedef __attribute__((ext_vector_type(8))) short bf16x8;   // 8 bf16 (4 VGPRs) — MFMA A/B frag
typedef __attribute__((ext_vector_type(4))) float f32x4;    // 16x16 MFMA C/D frag

#define DEV static __device__ __forceinline__

DEV unsigned short f2bf(float f) {          // manual RNE (cold paths)
  union { float f; uint32_t i; } u; u.f = f;
  uint32_t r = u.i + 0x7fffu + ((u.i >> 16) & 1u);
  return (unsigned short)(r >> 16);
}

DEV unsigned short f2bfn(float f) {         // native cast -> v_cvt (hot paths)
  union { __hip_bfloat16 h; unsigned short u; } c;
  c.h = __float2bfloat16(f);
  return c.u;
}

DEV float fast_exp2(float x) {              // bare v_exp_f32 (2^x), no libm guards
#if __has_builtin(__builtin_amdgcn_exp2f)
  return __builtin_amdgcn_exp2f(x);
#else
  return exp2f(x);
#endif
}

// async global->LDS, 16B per lane; LDS dest = wave-uniform base + lane*16
#define GL16(g, l) \
  __builtin_amdgcn_global_load_lds((const __attribute__((address_space(1))) void*)(g), \
                                   (__attribute__((address_space(3))) void*)(l), 16, 0, 0)

// ---------------------------------------------------------------------------
// 1) convert f32 -> bf16: hidden (4M), Wq(*0.125*log2e), Wk, Wv, Wo (1M each).
//    Tail blocks (>=8192) build the fused cos/sin float2 table cs[s][hd<32]
//    in d_out scratch (fully overwritten later by the Wo GEMM).
// ---------------------------------------------------------------------------
__global__ __launch_bounds__(256) void convert_all(
    const float* __restrict__ hid, const float* __restrict__ wq,
    const float* __restrict__ wk, const float* __restrict__ wv,
    const float* __restrict__ wo, unsigned short* __restrict__ out,
    const float* __restrict__ cosT, const float* __restrict__ sinT,
    float2* __restrict__ cst)
{
  if (blockIdx.x >= 8192) {                 // cs-table tail: 256 blocks, 65536 elems
    int idx = (blockIdx.x - 8192) * 256 + threadIdx.x;   // [0, 65536)
    int s = idx >> 5, hd = idx & 31;
    cst[idx] = make_float2(cosT[s * 64 + hd], sinT[s * 64 + hd]);
    return;
  }
  long i = ((long)blockIdx.x * 256 + threadIdx.x) * 4;
  const float* src; float scale = 1.0f;
  if (i < 4194304)      { src = hid + i; }
  else if (i < 5242880) { src = wq + (i - 4194304); scale = 0.18033688011112042f; }
  else if (i < 6291456) { src = wk + (i - 5242880); }
  else if (i < 7340032) { src = wv + (i - 6291456); }
  else                  { src = wo + (i - 7340032); }
  float4 v = *(const float4*)src;
  ushort4 o;
  o.x = f2bf(v.x * scale); o.y = f2bf(v.y * scale);
  o.z = f2bf(v.z * scale); o.w = f2bf(v.w * scale);
  *(ushort4*)(out + i) = o;
}

// ---------------------------------------------------------------------------
// 2) NT GEMM: C[M,N] = A[M,K] * B[N,K]^T, K=1024, bf16 in, 128x128 tile, BK=32
//    m97-style staging: global_load_lds dwordx4 into LINEAR LDS [128][32].
//    Fused QKV + RoPE. Q,K -> PAIRED layout [B*H][S][32][2]; V -> TRANSPOSED
//    [B*H][64][S].
// ---------------------------------------------------------------------------
__global__ __launch_bounds__(256) void gemm_qkv(
    const unsigned short* __restrict__ A,
    const unsigned short* __restrict__ B0, const unsigned short* __restrict__ B1,
    const unsigned short* __restrict__ B2,
    const float* __restrict__ csT,          // fused float2 cos/sin table
    unsigned short* __restrict__ qws, unsigned short* __restrict__ kws,
    unsigned short* __restrict__ vws)
{
  __shared__ unsigned short As[128 * 32];   // linear [row][32], 8KB
  __shared__ unsigned short Bs[128 * 32];
  const int tid  = threadIdx.x;
  const int lane = tid & 63;
  const int wave = tid >> 6;
  const int wr = wave >> 1, wc = wave & 1;
  const int m0 = blockIdx.x * 128;
  const int n0 = blockIdx.y * 128;

  const int sel = n0 >> 10;
  const unsigned short* Bsrc = (sel == 0) ? B0 : ((sel == 1) ? B1 : B2);
  const int nrel = n0 & 1023;

  const int grow = tid >> 2;        // 0..63: row within 64-row half
  const int gcol = (tid & 3) * 8;   // 8-elem chunk
  const int wuni = wave * 512;      // wave-uniform LDS base (ushorts)

  f32x4 acc[4][4] = {};

  for (int k0 = 0; k0 < 1024; k0 += 32) {
    GL16(A    + (long)(m0 + grow)        * 1024 + k0 + gcol, &As[wuni]);
    GL16(A    + (long)(m0 + 64 + grow)   * 1024 + k0 + gcol, &As[2048 + wuni]);
    GL16(Bsrc + (long)(nrel + grow)      * 1024 + k0 + gcol, &Bs[wuni]);
    GL16(Bsrc + (long)(nrel + 64 + grow) * 1024 + k0 + gcol, &Bs[2048 + wuni]);
    __syncthreads();

    bf16x8 af[4], bfr[4];
#pragma unroll
    for (int mi = 0; mi < 4; ++mi)
      af[mi] = *(const bf16x8*)&As[(wr * 64 + mi * 16 + (lane & 15)) * 32 + (lane >> 4) * 8];
#pragma unroll
    for (int ni = 0; ni < 4; ++ni)
      bfr[ni] = *(const bf16x8*)&Bs[(wc * 64 + ni * 16 + (lane & 15)) * 32 + (lane >> 4) * 8];
#pragma unroll
    for (int mi = 0; mi < 4; ++mi)
#pragma unroll
      for (int ni = 0; ni < 4; ++ni)
        acc[mi][ni] = __builtin_amdgcn_mfma_f32_16x16x32_bf16(af[mi], bfr[ni], acc[mi][ni], 0, 0, 0);
    __syncthreads();
  }

  const int h    = ((n0 & 1023) + wc * 64) >> 6;
  const int colb = lane & 15;
  if (sel < 2) {                 // Q or K: RoPE, paired layout [bh][s][32][2]
    unsigned short* dst = (sel == 0) ? qws : kws;
#pragma unroll
    for (int mi = 0; mi < 4; ++mi) {
#pragma unroll
      for (int r = 0; r < 4; ++r) {
        int row = m0 + wr * 64 + mi * 16 + (lane >> 4) * 4 + r;
        int b = row >> 11, s = row & 2047;
        long base = ((long)(b * 16 + h) * 2048 + s) * 64;
#pragma unroll
        for (int ni = 0; ni < 2; ++ni) {
          int hd = ni * 16 + colb;                          // < 32
          float2 cs = *(const float2*)(csT + (long)(s * 32 + hd) * 2);
          float v1 = acc[mi][ni][r];
          float v2 = acc[mi][ni + 2][r];
          ushort2 pr;
          pr.x = f2bf(v1 * cs.x - v2 * cs.y);               // logical hd
          pr.y = f2bf(v2 * cs.x + v1 * cs.y);               // logical hd+32
          *(ushort2*)(dst + base + 2 * hd) = pr;
        }
      }
    }
  } else {                       // V: store TRANSPOSED [bh][hd][s], ushort4 packs
#pragma unroll
    for (int mi = 0; mi < 4; ++mi) {
      int row0 = m0 + wr * 64 + mi * 16 + (lane >> 4) * 4;   // r=0..3 -> s0..s0+3
      int b = row0 >> 11, s0 = row0 & 2047;
      long hbase = (long)(b * 16 + h) * 64;
#pragma unroll
      for (int ni = 0; ni < 4; ++ni) {
        int hd = ni * 16 + colb;
        ushort4 v4;
        v4.x = f2bf(acc[mi][ni][0]); v4.y = f2bf(acc[mi][ni][1]);
        v4.z = f2bf(acc[mi][ni][2]); v4.w = f2bf(acc[mi][ni][3]);
        *(ushort4*)(vws + (hbase + hd) * 2048 + s0) = v4;
      }
    }
  }
}

// ---------------------------------------------------------------------------
// 2b) Wo GEMM, 64x128 tile (grid 64x8 = 512 blocks = 2 blocks/CU for the
//     m114-style implicit overlap the 2-barrier loop needs). Same validated
//     staging/fragment pattern: 1 A-GL16 + 2 B-GL16 per K-step; waves 2x2
//     over 32x64 sub-tiles, acc[2][4]. Output f32 [4096][1024].
// ---------------------------------------------------------------------------
__global__ __launch_bounds__(256) void gemm_wo(
    const unsigned short* __restrict__ A,   // attn bf16 [4096][1024]
    const unsigned short* __restrict__ B0,  // Wo bf16 [1024][1024]
    float* __restrict__ outF)
{
  __shared__ unsigned short As[64 * 32];    // 4KB
  __shared__ unsigned short Bs[128 * 32];   // 8KB
  const int tid  = threadIdx.x;
  const int lane = tid & 63;
  const int wave = tid >> 6;
  const int wr = wave >> 1, wc = wave & 1;  // 2x2 waves, 32x64 each
  const int m0 = blockIdx.x * 64;
  const int n0 = blockIdx.y * 128;

  const int grow = tid >> 2;
  const int gcol = (tid & 3) * 8;
  const int wuni = wave * 512;

  f32x4 acc[2][4] = {};

  for (int k0 = 0; k0 < 1024; k0 += 32) {
    GL16(A  + (long)(m0 + grow)      * 1024 + k0 + gcol, &As[wuni]);
    GL16(B0 + (long)(n0 + grow)      * 1024 + k0 + gcol, &Bs[wuni]);
    GL16(B0 + (long)(n0 + 64 + grow) * 1024 + k0 + gcol, &Bs[2048 + wuni]);
    __syncthreads();

    bf16x8 af[2], bfr[4];
#pragma unroll
    for (int mi = 0; mi < 2; ++mi)
      af[mi] = *(const bf16x8*)&As[(wr * 32 + mi * 16 + (lane & 15)) * 32 + (lane >> 4) * 8];
#pragma unroll
    for (int ni = 0; ni < 4; ++ni)
      bfr[ni] = *(const bf16x8*)&Bs[(wc * 64 + ni * 16 + (lane & 15)) * 32 + (lane >> 4) * 8];
#pragma unroll
    for (int mi = 0; mi < 2; ++mi)
#pragma unroll
      for (int ni = 0; ni < 4; ++ni)
        acc[mi][ni] = __builtin_amdgcn_mfma_f32_16x16x32_bf16(af[mi], bfr[ni], acc[mi][ni], 0, 0, 0);
    __syncthreads();
  }

#pragma unroll
  for (int mi = 0; mi < 2; ++mi)
#pragma unroll
    for (int r = 0; r < 4; ++r) {
      long row = m0 + wr * 32 + mi * 16 + (lane >> 4) * 4 + r;
#pragma unroll
      for (int ni = 0; ni < 4; ++ni)
        outF[row * 1024 + n0 + wc * 64 + ni * 16 + (lane & 15)] = acc[mi][ni][r];
    }
}

// ---------------------------------------------------------------------------
// 3) flash attention — round-14/16/18 validated version (byte-identical):
//    16x16 swapped-QK, KVBLK=64, LDS double-buffered (1 barrier/tile), bare
//    v_exp_f32 softmax. grid 512 (XCD-swizzled), 4 waves, 32 q-rows/wave.
// ---------------------------------------------------------------------------
#define KSTR 72   // 144B row stride: 16B-aligned, bank-spread

__global__ __launch_bounds__(256) void attn_fwd(
    const unsigned short* __restrict__ qws, const unsigned short* __restrict__ kws,
    const unsigned short* __restrict__ vtws, unsigned short* __restrict__ attn)
{
  __shared__ unsigned short K2[2][64 * KSTR];       // [buf][key][hd]
  __shared__ unsigned short V2[2][64 * KSTR];       // [buf][hd][key]
  __shared__ unsigned short Plds[4][16 * KSTR];     // [q][key] per wave
  const int tid = threadIdx.x, lane = tid & 63, wave = tid >> 6;
  const int bid = blockIdx.x;
  const int sid = (bid & 7) * 64 + (bid >> 3);      // XCD swizzle (bijective)
  const int bh = sid >> 4, qb = sid & 15;
  const unsigned short* Qp = qws  + (long)bh * 2048 * 64;
  const unsigned short* Kp = kws  + (long)bh * 2048 * 64;
  const unsigned short* Vp = vtws + (long)bh * 64 * 2048;   // [hd][S]
  const int q0w = qb * 128 + wave * 32;
  const int l15 = lane & 15, l16 = lane >> 4;

  bf16x8 qf[2][2];
#pragma unroll
  for (int sb = 0; sb < 2; ++sb)
#pragma unroll
    for (int st = 0; st < 2; ++st)
      qf[sb][st] = *(const bf16x8*)(Qp + (long)(q0w + sb * 16 + l15) * 64 + l16 * 8 + st * 32);

  f32x4 o[2][4] = {};
  float lrow[2] = {};               // per-lane partial row sum for q = l15

  const int kr_  = tid >> 3;        // K staging: key row
  const int c0_  = (tid & 7) * 8;   // K staging: hd chunk
  const int vhd_ = tid >> 2;        // V staging: hd row
  const int vko_ = (tid & 3) * 16;  // V staging: key chunk

  // prologue: tile 0 -> regs -> buf0
  bf16x8 kreg[2], vreg[2];
#pragma unroll
  for (int p = 0; p < 2; ++p) {
    kreg[p] = *(const bf16x8*)(Kp + (long)(p * 32 + kr_) * 64 + c0_);
    vreg[p] = *(const bf16x8*)(Vp + (long)vhd_ * 2048 + vko_ + p * 8);
  }
#pragma unroll
  for (int p = 0; p < 2; ++p) {
    *(bf16x8*)&K2[0][(p * 32 + kr_) * KSTR + c0_] = kreg[p];
    *(bf16x8*)&V2[0][vhd_ * KSTR + vko_ + p * 8]  = vreg[p];
  }

  // one tile body: compute buf CUR; prefetch tile (IT+1) and write to buf NXT.
#define TILE_BODY(CUR, NXT, IT)                                                        \
  {                                                                                    \
    __syncthreads();  /* orders: writes of CUR visible; prior reads of NXT done */     \
    const int nt = (IT) + 1;                                                           \
    if (nt < 32) {                                                                     \
      _Pragma("unroll")                                                                \
      for (int p = 0; p < 2; ++p) {                                                    \
        kreg[p] = *(const bf16x8*)(Kp + (long)(nt * 64 + p * 32 + kr_) * 64 + c0_);    \
        vreg[p] = *(const bf16x8*)(Vp + (long)vhd_ * 2048 + nt * 64 + vko_ + p * 8);   \
      }                                                                                \
    }                                                                                  \
    bf16x8 kb[2][4], vb[2][4];                                                         \
    _Pragma("unroll")                                                                  \
    for (int st = 0; st < 2; ++st)                                                     \
      _Pragma("unroll")                                                                \
      for (int ni = 0; ni < 4; ++ni) {                                                 \
        kb[st][ni] = *(const bf16x8*)&K2[CUR][(ni * 16 + l15) * KSTR + l16 * 8 + st * 32]; \
        vb[st][ni] = *(const bf16x8*)&V2[CUR][(ni * 16 + l15) * KSTR + l16 * 8 + st * 32]; \
      }                                                                                \
    _Pragma("unroll")                                                                  \
    for (int sb = 0; sb < 2; ++sb) {                                                   \
      f32x4 sf[4] = {};                                                                \
      __builtin_amdgcn_s_setprio(1);                                                   \
      _Pragma("unroll")                                                                \
      for (int st = 0; st < 2; ++st)                                                   \
        _Pragma("unroll")                                                              \
        for (int ni = 0; ni < 4; ++ni)                                                 \
          sf[ni] = __builtin_amdgcn_mfma_f32_16x16x32_bf16(kb[st][ni], qf[sb][st], sf[ni], 0, 0, 0); \
      __builtin_amdgcn_s_setprio(0);                                                   \
      _Pragma("unroll")                                                                \
      for (int ni = 0; ni < 4; ++ni) {                                                 \
        float e0 = fast_exp2(sf[ni][0]), e1 = fast_exp2(sf[ni][1]);                    \
        float e2 = fast_exp2(sf[ni][2]), e3 = fast_exp2(sf[ni][3]);                    \
        lrow[sb] += (e0 + e1) + (e2 + e3);                                             \
        uint2 pk;                                                                      \
        pk.x = (uint32_t)f2bfn(e0) | ((uint32_t)f2bfn(e1) << 16);                      \
        pk.y = (uint32_t)f2bfn(e2) | ((uint32_t)f2bfn(e3) << 16);                      \
        *(uint2*)&Plds[wave][l15 * KSTR + ni * 16 + l16 * 4] = pk;                     \
      }                                                                                \
      __builtin_amdgcn_s_setprio(1);                                                   \
      _Pragma("unroll")                                                                \
      for (int st = 0; st < 2; ++st) {                                                 \
        bf16x8 pa = *(const bf16x8*)&Plds[wave][l15 * KSTR + l16 * 8 + st * 32];       \
        _Pragma("unroll")                                                              \
        for (int ni = 0; ni < 4; ++ni)                                                 \
          o[sb][ni] = __builtin_amdgcn_mfma_f32_16x16x32_bf16(pa, vb[st][ni], o[sb][ni], 0, 0, 0); \
      }                                                                                \
      __builtin_amdgcn_s_setprio(0);                                                   \
    }                                                                                  \
    if (nt < 32) {                                                                     \
      _Pragma("unroll")                                                                \
      for (int p = 0; p < 2; ++p) {                                                    \
        *(bf16x8*)&K2[NXT][(p * 32 + kr_) * KSTR + c0_] = kreg[p];                     \
        *(bf16x8*)&V2[NXT][vhd_ * KSTR + vko_ + p * 8]  = vreg[p];                     \
      }                                                                                \
    }                                                                                  \
  }

  for (int it = 0; it < 32; it += 2) {
    TILE_BODY(0, 1, it);
    TILE_BODY(1, 0, it + 1);
  }
#undef TILE_BODY

  // ---- epilogue: reduce l over lane groups (q=l15), redistribute, store ----
  const int b = bh >> 4, h = bh & 15;
  float linv[2];
#pragma unroll
  for (int sb = 0; sb < 2; ++sb) {
    float t = lrow[sb];
    t += __shfl_xor(t, 16, 64);
    t += __shfl_xor(t, 32, 64);
    linv[sb] = 1.0f / t;
  }
#pragma unroll
  for (int sb = 0; sb < 2; ++sb)
#pragma unroll
    for (int r = 0; r < 4; ++r) {
      float lv = __shfl(linv[sb], l16 * 4 + r, 64);   // fetch 1/l for q=(l16*4+r)
      int qrow = q0w + sb * 16 + l16 * 4 + r;
#pragma unroll
      for (int ni = 0; ni < 4; ++ni) {
        float val = o[sb][ni][r] * lv;
        attn[((long)(b * 2048 + qrow) * 16 + h) * 64 + ni * 16 + l15] = f2bfn(val);
      }
    }
}

// ---------------------------------------------------------------------------
// launcher
// ---------------------------------------------------------------------------
extern "C" void kernel_launch(void* const* d_in, const int* in_sizes, int n_in,
                              void* d_out, int out_size, void* d_ws, size_t ws_size,
                              hipStream_t stream)
{
  const float* hid  = (const float*)d_in[0];
  const float* cosT = (const float*)d_in[2];
  const float* sinT = (const float*)d_in[3];
  const float* wq   = (const float*)d_in[4];
  const float* wk   = (const float*)d_in[5];
  const float* wv   = (const float*)d_in[6];
  const float* wo   = (const float*)d_in[7];

  unsigned short* ws   = (unsigned short*)d_ws;
  unsigned short* xbf  = ws;
  unsigned short* wqbf = ws + 4194304;
  unsigned short* wkbf = ws + 5242880;
  unsigned short* wvbf = ws + 6291456;
  unsigned short* wobf = ws + 7340032;
  unsigned short* qws  = ws + 8388608;
  unsigned short* kws  = ws + 12582912;
  unsigned short* vtws = ws + 16777216;   // [bh][hd][S] (transposed V)
  unsigned short* attn = ws;              // reuse xbf (dead after QKV GEMM)
  float* outF = (float*)d_out;
  float2* cstab = (float2*)d_out;         // 512KB scratch; Wo GEMM overwrites all

  convert_all<<<8448, 256, 0, stream>>>(hid, wq, wk, wv, wo, ws, cosT, sinT, cstab);
  gemm_qkv<<<dim3(32, 24), 256, 0, stream>>>(xbf, wqbf, wkbf, wvbf, (const float*)cstab,
                                             qws, kws, vtws);
  attn_fwd<<<512, 256, 0, stream>>>(qws, kws, vtws, attn);
  gemm_wo<<<dim3(64, 8), 256, 0, stream>>>(attn, wobf, outF);
}